// Round 4
// baseline (182.093 us; speedup 1.0000x reference)
//
#include <hip/hip_runtime.h>
#include <stdint.h>

#define N_DIM 4096
#define B_DIM 64
#define OUTSZ (B_DIM * N_DIM)        // 262144 elements per output plane

typedef __bf16 bf16x8 __attribute__((ext_vector_type(8)));
typedef float floatx4 __attribute__((ext_vector_type(4)));

union FragU { uint4 u; bf16x8 h; };

__device__ __forceinline__ unsigned short f2bf_rne(float f) {
    unsigned int u = __float_as_uint(f);
    u += 0x7fffu + ((u >> 16) & 1u);
    return (unsigned short)(u >> 16);
}

// c = Vmag*cos(ang), s = Vmag*sin(ang).
// fp32 copies in natural [b][j] layout (epilogue), bf16 copies packed in MFMA
// B-fragment order: idx = ((j>>3)*64 + b)*8 + (j&7)
__global__ __launch_bounds__(256) void pf_prep(
        const float* __restrict__ Vmag, const float* __restrict__ Vang,
        unsigned short* __restrict__ c_pk, unsigned short* __restrict__ s_pk,
        float* __restrict__ c_f, float* __restrict__ s_f) {
    int idx = blockIdx.x * 256 + threadIdx.x;   // = b*4096 + j
    int b = idx >> 12;
    int j = idx & 4095;
    float sv, cv;
    sincosf(Vang[idx], &sv, &cv);
    float v = Vmag[idx];
    float c = v * cv;
    float s = v * sv;
    c_f[idx] = c;
    s_f[idx] = s;
    int p = (((j >> 3) << 6) + b) * 8 + (j & 7);
    c_pk[p] = f2bf_rne(c);
    s_pk[p] = f2bf_rne(s);
}

// K-split partial GEMM. Grid 256 = 64 row-groups x 4 K-chunks.
// Block: 64 rows x K=1024, 16 waves = 4 row-stripes x 4 K-quarters (256 each).
// Wave tile: 16 rows x 64 b. X = G*c + B*s ; Y = G*s - B*c (-c via sign XOR).
// Partials (fp32 X,Y per K-chunk) written to ws in [b][row] layout (float4 of
// 4 consecutive rows per lane -> full 64B lines). Per-block bytes ~800KB
// (vs 1.5MB before) to get under the ~28 GB/s/CU vector-memory ceiling.
__global__ __launch_bounds__(1024, 4) void pf_gemm(
        const float* __restrict__ G, const float* __restrict__ Bm,
        const unsigned short* __restrict__ c_pk, const unsigned short* __restrict__ s_pk,
        float* __restrict__ ws_part) {
    __shared__ float redX[3][4][16][66];   // [src kq-1][stripe][m][b] pad66 -> 2-way max
    __shared__ float redY[3][4][16][66];
    const int tid = threadIdx.x;
    const int wave = tid >> 6;        // 0..15
    const int lane = tid & 63;
    const int n = lane & 15;          // A: row ; B/C: col b
    const int quad = lane >> 4;       // k-subgroup of 8 / C row-group of 4
    const int kc = blockIdx.x & 3;    // K-chunk (1024)
    const int rg = blockIdx.x >> 2;   // row group (64 rows)
    const int stripe = wave & 3;      // 16-row stripe
    const int kq = wave >> 2;         // K-quarter (256)

    const int row = (rg << 6) + (stripe << 4) + n;
    const int kb = (kc << 10) + (kq << 8);

    const float* gp = G  + (size_t)row * N_DIM + kb + (quad << 3);
    const float* bp = Bm + (size_t)row * N_DIM + kb + (quad << 3);
    const unsigned short* cp = c_pk + ((size_t)((kb >> 3) + quad) * 64 + n) * 8;
    const unsigned short* sp = s_pk + ((size_t)((kb >> 3) + quad) * 64 + n) * 8;

    floatx4 accX[4], accY[4];
    #pragma unroll
    for (int t = 0; t < 4; ++t) {
        accX[t] = (floatx4){0.f, 0.f, 0.f, 0.f};
        accY[t] = (floatx4){0.f, 0.f, 0.f, 0.f};
    }

    // preload iter 0's A operands
    float4 g0 = *(const float4*)gp;
    float4 g1 = *(const float4*)(gp + 4);
    float4 h0 = *(const float4*)bp;
    float4 h1 = *(const float4*)(bp + 4);
    gp += 32; bp += 32;

    #pragma unroll 1
    for (int it = 0; it < 8; ++it) {
        // issue c/s fragment loads FIRST (so waiting on them never drains the
        // A-prefetch issued after them — vmcnt retires in order)
        uint4 cu[4], su[4];
        #pragma unroll
        for (int t = 0; t < 4; ++t) cu[t] = *(const uint4*)(cp + t * 128);
        #pragma unroll
        for (int t = 0; t < 4; ++t) su[t] = *(const uint4*)(sp + t * 128);
        cp += 2048; sp += 2048;

        float4 ng0, ng1, nh0, nh1;
        if (it < 7) {                 // prefetch next iter's A
            ng0 = *(const float4*)gp;
            ng1 = *(const float4*)(gp + 4);
            nh0 = *(const float4*)bp;
            nh1 = *(const float4*)(bp + 4);
            gp += 32; bp += 32;
        }

        bf16x8 ag, ah;
        ag[0] = (__bf16)g0.x; ag[1] = (__bf16)g0.y; ag[2] = (__bf16)g0.z; ag[3] = (__bf16)g0.w;
        ag[4] = (__bf16)g1.x; ag[5] = (__bf16)g1.y; ag[6] = (__bf16)g1.z; ag[7] = (__bf16)g1.w;
        ah[0] = (__bf16)h0.x; ah[1] = (__bf16)h0.y; ah[2] = (__bf16)h0.z; ah[3] = (__bf16)h0.w;
        ah[4] = (__bf16)h1.x; ah[5] = (__bf16)h1.y; ah[6] = (__bf16)h1.z; ah[7] = (__bf16)h1.w;

        // c-phase: X += G*c ; Y += B*(-c)
        #pragma unroll
        for (int t = 0; t < 4; ++t) {
            FragU cf, nf;
            cf.u = cu[t];
            nf.u.x = cu[t].x ^ 0x80008000u;
            nf.u.y = cu[t].y ^ 0x80008000u;
            nf.u.z = cu[t].z ^ 0x80008000u;
            nf.u.w = cu[t].w ^ 0x80008000u;
            accX[t] = __builtin_amdgcn_mfma_f32_16x16x32_bf16(ag, cf.h, accX[t], 0, 0, 0);
            accY[t] = __builtin_amdgcn_mfma_f32_16x16x32_bf16(ah, nf.h, accY[t], 0, 0, 0);
        }
        // s-phase: X += B*s ; Y += G*s
        #pragma unroll
        for (int t = 0; t < 4; ++t) {
            FragU sf;
            sf.u = su[t];
            accX[t] = __builtin_amdgcn_mfma_f32_16x16x32_bf16(ah, sf.h, accX[t], 0, 0, 0);
            accY[t] = __builtin_amdgcn_mfma_f32_16x16x32_bf16(ag, sf.h, accY[t], 0, 0, 0);
        }

        if (it < 7) { g0 = ng0; g1 = ng1; h0 = nh0; h1 = nh1; }
    }

    // intra-block reduction over the 4 K-quarters.
    // C/D layout: col(b) = lane&15 (+16t), row(m) = quad*4 + r
    if (kq > 0) {
        #pragma unroll
        for (int t = 0; t < 4; ++t)
            #pragma unroll
            for (int r = 0; r < 4; ++r) {
                redX[kq - 1][stripe][(quad << 2) + r][(t << 4) + n] = accX[t][r];
                redY[kq - 1][stripe][(quad << 2) + r][(t << 4) + n] = accY[t][r];
            }
    }
    __syncthreads();
    if (kq == 0) {
        #pragma unroll
        for (int t = 0; t < 4; ++t)
            #pragma unroll
            for (int r = 0; r < 4; ++r) {
                float x = accX[t][r], y = accY[t][r];
                #pragma unroll
                for (int w = 0; w < 3; ++w) {
                    x += redX[w][stripe][(quad << 2) + r][(t << 4) + n];
                    y += redY[w][stripe][(quad << 2) + r][(t << 4) + n];
                }
                accX[t][r] = x; accY[t][r] = y;
            }
        // write partials: plane layout off = col*4096 + row; accX[t] holds 4
        // consecutive rows (quad*4 + 0..3) of col t*16+n -> float4 store.
        float* wsX = ws_part + (size_t)kc * OUTSZ;
        float* wsY = ws_part + (size_t)(4 + kc) * OUTSZ;
        const int rowbase = (rg << 6) + (stripe << 4) + (quad << 2);
        #pragma unroll
        for (int t = 0; t < 4; ++t) {
            size_t off = (size_t)((t << 4) + n) * N_DIM + rowbase;
            *(float4*)(wsX + off) = (float4){accX[t][0], accX[t][1], accX[t][2], accX[t][3]};
            *(float4*)(wsY + off) = (float4){accY[t][0], accY[t][1], accY[t][2], accY[t][3]};
        }
    }
}

// Sum the 4 K-chunk partials + fused epilogue. All arrays share off=b*4096+i.
__global__ __launch_bounds__(256) void pf_reduce(
        const float* __restrict__ ws_part,
        const float* __restrict__ c_f, const float* __restrict__ s_f,
        const float* __restrict__ P_in, const float* __restrict__ Q_in,
        float* __restrict__ out) {
    int e = (blockIdx.x * 256 + threadIdx.x) * 4;
    float4 X = *(const float4*)(ws_part + e);
    float4 Y = *(const float4*)(ws_part + 4 * OUTSZ + e);
    #pragma unroll
    for (int kc = 1; kc < 4; ++kc) {
        float4 x = *(const float4*)(ws_part + (size_t)kc * OUTSZ + e);
        float4 y = *(const float4*)(ws_part + (size_t)(4 + kc) * OUTSZ + e);
        X.x += x.x; X.y += x.y; X.z += x.z; X.w += x.w;
        Y.x += y.x; Y.y += y.y; Y.z += y.z; Y.w += y.w;
    }
    float4 c = *(const float4*)(c_f + e);
    float4 s = *(const float4*)(s_f + e);
    float4 P = *(const float4*)(P_in + e);
    float4 Q = *(const float4*)(Q_in + e);
    float4 rp, rq;
    rp.x = c.x * X.x + s.x * Y.x - P.x;  rq.x = s.x * X.x - c.x * Y.x - Q.x;
    rp.y = c.y * X.y + s.y * Y.y - P.y;  rq.y = s.y * X.y - c.y * Y.y - Q.y;
    rp.z = c.z * X.z + s.z * Y.z - P.z;  rq.z = s.z * X.z - c.z * Y.z - Q.z;
    rp.w = c.w * X.w + s.w * Y.w - P.w;  rq.w = s.w * X.w - c.w * Y.w - Q.w;
    *(float4*)(out + e) = rp;
    *(float4*)(out + OUTSZ + e) = rq;
}

extern "C" void kernel_launch(void* const* d_in, const int* in_sizes, int n_in,
                              void* d_out, int out_size, void* d_ws, size_t ws_size,
                              hipStream_t stream) {
    const float* Vmag = (const float*)d_in[0];
    const float* Vang = (const float*)d_in[1];
    const float* P_in = (const float*)d_in[2];
    const float* Q_in = (const float*)d_in[3];
    const float* G    = (const float*)d_in[4];
    const float* Bm   = (const float*)d_in[5];
    float* out = (float*)d_out;

    char* ws = (char*)d_ws;
    unsigned short* c_pk = (unsigned short*)(ws);                    // 512 KB
    unsigned short* s_pk = (unsigned short*)(ws + (512u << 10));     // 512 KB
    float* c_f = (float*)(ws + (1u << 20));                          // 1 MB
    float* s_f = (float*)(ws + (2u << 20));                          // 1 MB
    float* ws_part = (float*)(ws + (3u << 20));                      // 8 MB

    hipLaunchKernelGGL(pf_prep, dim3((B_DIM * N_DIM) / 256), dim3(256), 0, stream,
                       Vmag, Vang, c_pk, s_pk, c_f, s_f);
    hipLaunchKernelGGL(pf_gemm, dim3(256), dim3(1024), 0, stream,
                       G, Bm, c_pk, s_pk, ws_part);
    hipLaunchKernelGGL(pf_reduce, dim3(OUTSZ / 1024), dim3(256), 0, stream,
                       ws_part, c_f, s_f, P_in, Q_in, out);
}

// Round 5
// 170.640 us; speedup vs baseline: 1.0671x; 1.0671x over previous
//
#include <hip/hip_runtime.h>
#include <stdint.h>

#define N_DIM 4096
#define B_DIM 64
#define OUTSZ (B_DIM * N_DIM)        // 262144 elements per output plane

typedef __bf16 bf16x8 __attribute__((ext_vector_type(8)));
typedef float floatx4 __attribute__((ext_vector_type(4)));

union FragU { uint4 u; bf16x8 h; };

#define AS1 __attribute__((address_space(1)))
#define AS3 __attribute__((address_space(3)))

__device__ __forceinline__ void gll16(const void* gp, void* lp) {
    // 64 lanes x 16B: per-lane global src -> LDS uniform base + lane*16
    __builtin_amdgcn_global_load_lds((const AS1 void*)gp, (AS3 void*)lp, 16, 0, 0);
}

__device__ __forceinline__ unsigned short f2bf_rne(float f) {
    unsigned int u = __float_as_uint(f);
    u += 0x7fffu + ((u >> 16) & 1u);
    return (unsigned short)(u >> 16);
}

// c = Vmag*cos(ang), s = Vmag*sin(ang).
// fp32 copies in natural [b][j] layout (epilogue), bf16 copies packed in MFMA
// B-fragment order: idx = ((j>>3)*64 + b)*8 + (j&7)
__global__ __launch_bounds__(256) void pf_prep(
        const float* __restrict__ Vmag, const float* __restrict__ Vang,
        unsigned short* __restrict__ c_pk, unsigned short* __restrict__ s_pk,
        float* __restrict__ c_f, float* __restrict__ s_f) {
    int idx = blockIdx.x * 256 + threadIdx.x;   // = b*4096 + j
    int b = idx >> 12;
    int j = idx & 4095;
    float sv, cv;
    sincosf(Vang[idx], &sv, &cv);
    float v = Vmag[idx];
    float c = v * cv;
    float s = v * sv;
    c_f[idx] = c;
    s_f[idx] = s;
    int p = (((j >> 3) << 6) + b) * 8 + (j & 7);
    c_pk[p] = f2bf_rne(c);
    s_pk[p] = f2bf_rne(s);
}

// K-split GEMM, TA-traffic-minimized. Grid 256 = 64 rowgroups x 4 K-chunks.
// Block: 64 rows x K=1024, 16 waves = 4 row-stripes x 4 k-subchunks(q).
// c/s for the block's K-slice staged into LDS ONCE (4 phases of K=256,
// double-buffered 64KB, global_load_lds) -> all stripes read frags from LDS.
// A (G/B) direct prefetched global loads (each byte read exactly once).
// Per-block TA bytes: 512K (A) + 256K (c/s) + 32K (ws) vs 1.6M in R4.
// X = G*c + B*s ; Y = G*s - B*c (-c via sign-bit XOR).
__global__ __launch_bounds__(1024, 4) void pf_gemm(
        const float* __restrict__ G, const float* __restrict__ Bm,
        const unsigned short* __restrict__ c_pk, const unsigned short* __restrict__ s_pk,
        float* __restrict__ ws_part) {
    __shared__ __align__(16) unsigned short cs[2][2][16384];  // [buf][c|s][slice] 128KB
    const int tid = threadIdx.x;
    const int wave = tid >> 6;        // 0..15
    const int lane = tid & 63;
    const int n = lane & 15;          // A: row ; B/C: col b
    const int quad = lane >> 4;       // k-subgroup of 8 / C row-group of 4
    const int kc = blockIdx.x & 3;    // K-chunk (1024)
    const int rg = blockIdx.x >> 2;   // row group (64 rows)
    const int stripe = wave & 3;      // 16-row stripe
    const int q = wave >> 2;          // k-subchunk (64 within each phase... see map)

    const int row = (rg << 6) + (stripe << 4) + n;
    const int kbase = kc << 10;

    // A base: wave q's k-offset q*64; per step (p,i): + p*256 + i*32
    const float* gp0 = G  + (size_t)row * N_DIM + kbase + (q << 6) + (quad << 3);
    const float* bp0 = Bm + (size_t)row * N_DIM + kbase + (q << 6) + (quad << 3);

    // staging: phase p slice = c_pk[kc*65536 + p*16384 .. +16384); 32 instrs of
    // 512 ushorts per array; wave w takes instrs {2w, 2w+1}
    const int sj = wave << 1;
    const unsigned short* csrc = c_pk + (kc << 16) + (sj << 9) + (lane << 3);
    const unsigned short* ssrc = s_pk + (kc << 16) + (sj << 9) + (lane << 3);

    auto stage = [&](int p) {
        const int bp = p & 1;
        const unsigned short* c0 = csrc + (p << 14);
        const unsigned short* s0 = ssrc + (p << 14);
        gll16(c0,       &cs[bp][0][sj << 9]);
        gll16(c0 + 512, &cs[bp][0][(sj + 1) << 9]);
        gll16(s0,       &cs[bp][1][sj << 9]);
        gll16(s0 + 512, &cs[bp][1][(sj + 1) << 9]);
    };

    floatx4 accX[4], accY[4];
    #pragma unroll
    for (int t = 0; t < 4; ++t) {
        accX[t] = (floatx4){0.f, 0.f, 0.f, 0.f};
        accY[t] = (floatx4){0.f, 0.f, 0.f, 0.f};
    }

    stage(0);
    // preload step 0's A operands (independent of LDS)
    float4 g0 = *(const float4*)gp0;
    float4 g1 = *(const float4*)(gp0 + 4);
    float4 h0 = *(const float4*)bp0;
    float4 h1 = *(const float4*)(bp0 + 4);

    #pragma unroll
    for (int p = 0; p < 4; ++p) {
        __syncthreads();              // phase p's staging (and prior reads) done
        if (p < 3) stage(p + 1);      // overlaps with phase p compute
        const int bp = p & 1;

        #pragma unroll
        for (int i = 0; i < 2; ++i) {
            const int pi = (p << 1) + i;
            float4 ng0, ng1, nh0, nh1;
            if (pi < 7) {             // prefetch next step's A
                const int noff = (((pi + 1) >> 1) << 8) + (((pi + 1) & 1) << 5);
                const float* gn = gp0 + noff;
                const float* bn = bp0 + noff;
                ng0 = *(const float4*)gn; ng1 = *(const float4*)(gn + 4);
                nh0 = *(const float4*)bn; nh1 = *(const float4*)(bn + 4);
            }

            // c/s fragments from LDS: kgroup_local = q*8 + i*4 + quad
            const int kl = (((q << 1) + i) << 2) + quad;
            const unsigned short* cl = &cs[bp][0][(kl << 9) + (n << 3)];
            const unsigned short* sl = &cs[bp][1][(kl << 9) + (n << 3)];
            uint4 cu[4], su[4];
            #pragma unroll
            for (int t = 0; t < 4; ++t) cu[t] = *(const uint4*)(cl + (t << 7));
            #pragma unroll
            for (int t = 0; t < 4; ++t) su[t] = *(const uint4*)(sl + (t << 7));

            bf16x8 ag, ah;
            ag[0] = (__bf16)g0.x; ag[1] = (__bf16)g0.y; ag[2] = (__bf16)g0.z; ag[3] = (__bf16)g0.w;
            ag[4] = (__bf16)g1.x; ag[5] = (__bf16)g1.y; ag[6] = (__bf16)g1.z; ag[7] = (__bf16)g1.w;
            ah[0] = (__bf16)h0.x; ah[1] = (__bf16)h0.y; ah[2] = (__bf16)h0.z; ah[3] = (__bf16)h0.w;
            ah[4] = (__bf16)h1.x; ah[5] = (__bf16)h1.y; ah[6] = (__bf16)h1.z; ah[7] = (__bf16)h1.w;

            // c-phase: X += G*c ; Y += B*(-c)
            #pragma unroll
            for (int t = 0; t < 4; ++t) {
                FragU cf, nf;
                cf.u = cu[t];
                nf.u.x = cu[t].x ^ 0x80008000u;
                nf.u.y = cu[t].y ^ 0x80008000u;
                nf.u.z = cu[t].z ^ 0x80008000u;
                nf.u.w = cu[t].w ^ 0x80008000u;
                accX[t] = __builtin_amdgcn_mfma_f32_16x16x32_bf16(ag, cf.h, accX[t], 0, 0, 0);
                accY[t] = __builtin_amdgcn_mfma_f32_16x16x32_bf16(ah, nf.h, accY[t], 0, 0, 0);
            }
            // s-phase: X += B*s ; Y += G*s
            #pragma unroll
            for (int t = 0; t < 4; ++t) {
                FragU sf;
                sf.u = su[t];
                accX[t] = __builtin_amdgcn_mfma_f32_16x16x32_bf16(ah, sf.h, accX[t], 0, 0, 0);
                accY[t] = __builtin_amdgcn_mfma_f32_16x16x32_bf16(ag, sf.h, accY[t], 0, 0, 0);
            }

            if (pi < 7) { g0 = ng0; g1 = ng1; h0 = nh0; h1 = nh1; }
        }
    }

    // intra-block reduction over the 4 q-groups, LDS aliased over staging bufs.
    // C/D layout: col(b) = lane&15 (+16t), row(m) = quad*4 + r
    float* red = (float*)&cs[0][0][0];   // needs 101376B <= 131072B
    #define RX(k, s_, m, b) red[((((k) * 4 + (s_)) * 16 + (m)) * 66) + (b)]
    #define RY(k, s_, m, b) red[12672 + ((((k) * 4 + (s_)) * 16 + (m)) * 66) + (b)]
    __syncthreads();
    if (q > 0) {
        #pragma unroll
        for (int t = 0; t < 4; ++t)
            #pragma unroll
            for (int r = 0; r < 4; ++r) {
                RX(q - 1, stripe, (quad << 2) + r, (t << 4) + n) = accX[t][r];
                RY(q - 1, stripe, (quad << 2) + r, (t << 4) + n) = accY[t][r];
            }
    }
    __syncthreads();
    if (q == 0) {
        #pragma unroll
        for (int t = 0; t < 4; ++t)
            #pragma unroll
            for (int r = 0; r < 4; ++r) {
                float x = accX[t][r], y = accY[t][r];
                #pragma unroll
                for (int w = 0; w < 3; ++w) {
                    x += RX(w, stripe, (quad << 2) + r, (t << 4) + n);
                    y += RY(w, stripe, (quad << 2) + r, (t << 4) + n);
                }
                accX[t][r] = x; accY[t][r] = y;
            }
        // partials: plane off = col*4096 + row; accX[t] holds rows quad*4+0..3
        float* wsX = ws_part + (size_t)kc * OUTSZ;
        float* wsY = ws_part + (size_t)(4 + kc) * OUTSZ;
        const int rowbase = (rg << 6) + (stripe << 4) + (quad << 2);
        #pragma unroll
        for (int t = 0; t < 4; ++t) {
            size_t off = (size_t)((t << 4) + n) * N_DIM + rowbase;
            *(float4*)(wsX + off) = (float4){accX[t][0], accX[t][1], accX[t][2], accX[t][3]};
            *(float4*)(wsY + off) = (float4){accY[t][0], accY[t][1], accY[t][2], accY[t][3]};
        }
    }
}

// Sum the 4 K-chunk partials + fused epilogue. All arrays share off=b*4096+i.
__global__ __launch_bounds__(256) void pf_reduce(
        const float* __restrict__ ws_part,
        const float* __restrict__ c_f, const float* __restrict__ s_f,
        const float* __restrict__ P_in, const float* __restrict__ Q_in,
        float* __restrict__ out) {
    int e = (blockIdx.x * 256 + threadIdx.x) * 4;
    float4 X = *(const float4*)(ws_part + e);
    float4 Y = *(const float4*)(ws_part + 4 * OUTSZ + e);
    #pragma unroll
    for (int kc = 1; kc < 4; ++kc) {
        float4 x = *(const float4*)(ws_part + (size_t)kc * OUTSZ + e);
        float4 y = *(const float4*)(ws_part + (size_t)(4 + kc) * OUTSZ + e);
        X.x += x.x; X.y += x.y; X.z += x.z; X.w += x.w;
        Y.x += y.x; Y.y += y.y; Y.z += y.z; Y.w += y.w;
    }
    float4 c = *(const float4*)(c_f + e);
    float4 s = *(const float4*)(s_f + e);
    float4 P = *(const float4*)(P_in + e);
    float4 Q = *(const float4*)(Q_in + e);
    float4 rp, rq;
    rp.x = c.x * X.x + s.x * Y.x - P.x;  rq.x = s.x * X.x - c.x * Y.x - Q.x;
    rp.y = c.y * X.y + s.y * Y.y - P.y;  rq.y = s.y * X.y - c.y * Y.y - Q.y;
    rp.z = c.z * X.z + s.z * Y.z - P.z;  rq.z = s.z * X.z - c.z * Y.z - Q.z;
    rp.w = c.w * X.w + s.w * Y.w - P.w;  rq.w = s.w * X.w - c.w * Y.w - Q.w;
    *(float4*)(out + e) = rp;
    *(float4*)(out + OUTSZ + e) = rq;
}

extern "C" void kernel_launch(void* const* d_in, const int* in_sizes, int n_in,
                              void* d_out, int out_size, void* d_ws, size_t ws_size,
                              hipStream_t stream) {
    const float* Vmag = (const float*)d_in[0];
    const float* Vang = (const float*)d_in[1];
    const float* P_in = (const float*)d_in[2];
    const float* Q_in = (const float*)d_in[3];
    const float* G    = (const float*)d_in[4];
    const float* Bm   = (const float*)d_in[5];
    float* out = (float*)d_out;

    char* ws = (char*)d_ws;
    unsigned short* c_pk = (unsigned short*)(ws);                    // 512 KB
    unsigned short* s_pk = (unsigned short*)(ws + (512u << 10));     // 512 KB
    float* c_f = (float*)(ws + (1u << 20));                          // 1 MB
    float* s_f = (float*)(ws + (2u << 20));                          // 1 MB
    float* ws_part = (float*)(ws + (3u << 20));                      // 8 MB

    hipLaunchKernelGGL(pf_prep, dim3((B_DIM * N_DIM) / 256), dim3(256), 0, stream,
                       Vmag, Vang, c_pk, s_pk, c_f, s_f);
    hipLaunchKernelGGL(pf_gemm, dim3(256), dim3(1024), 0, stream,
                       G, Bm, c_pk, s_pk, ws_part);
    hipLaunchKernelGGL(pf_reduce, dim3(OUTSZ / 1024), dim3(256), 0, stream,
                       ws_part, c_f, s_f, P_in, Q_in, out);
}